// Round 9
// baseline (187.030 us; speedup 1.0000x reference)
//
#include <hip/hip_runtime.h>
#include <math.h>

#define Hh 128
#define Ww 128
#define HW (128*128)
#define PITCH 130
#define PADPX (130*130)

typedef unsigned short u16;
typedef unsigned int uint;
typedef _Float16 f16;
typedef __attribute__((ext_vector_type(8))) _Float16 f16x8;
typedef __attribute__((ext_vector_type(4))) _Float16 f16x4;
typedef __attribute__((ext_vector_type(4))) float f32x4;

// ---------------- zero halo edges of padded NHWC f16 buffer ----------------
__global__ __launch_bounds__(256) void zero_edge_k(u16* __restrict__ buf, int cu16) {
  int per_px = cu16 >> 3;           // uint4 chunks per pixel
  int total = 516 * per_px;
  int idx = blockIdx.x * 256 + threadIdx.x;
  int b = blockIdx.y;
  if (idx >= total) return;
  int e = idx / per_px, q = idx - e * per_px;
  int y, x;
  if (e < 130)      { y = 0;   x = e; }
  else if (e < 260) { y = 129; x = e - 130; }
  else { int j = e - 260; y = 1 + (j >> 1); x = (j & 1) ? 129 : 0; }
  *(uint4*)&buf[((size_t)b * PADPX + (size_t)(y * PITCH + x)) * cu16 + q * 8] =
      make_uint4(0, 0, 0, 0);
}

// ---------------- prep: cond [B][133][HW] f32 -> padded NHWC f16 [B][PADPX][160] ----------------
__global__ __launch_bounds__(256) void prep_cond_k(const float* __restrict__ cond,
                                                   f16* __restrict__ out) {
  int p = blockIdx.x * 256 + threadIdx.x;
  int b = blockIdx.y;
  int y = p >> 7, x = p & 127;
  const float* cb = cond + (size_t)b * 133 * HW + p;
  f16* ob = out + ((size_t)b * PADPX + (size_t)((y + 1) * PITCH + x + 1)) * 160;
  for (int c = 0; c < 160; c += 8) {
    f16 buf[8];
    #pragma unroll
    for (int j = 0; j < 8; j++) {
      float v = (c + j < 133) ? cb[(size_t)(c + j) * HW] : 0.f;
      buf[j] = (f16)v;
    }
    *(uint4*)&ob[c] = *(uint4*)buf;
  }
}

// ---------------- conv weight -> f16 MFMA A-frags: frag = (t*NC + c)*NCOF + f ----------------
__global__ __launch_bounds__(256) void wtrans_mfma_k(const float* __restrict__ w,
                                                     f16* __restrict__ wt,
                                                     int CIN, int NC, int NCOF) {
  int idx = blockIdx.x * 256 + threadIdx.x;
  int total = 9 * NC * NCOF * 64;
  if (idx >= total) return;
  int lane = idx & 63;
  int frag = idx >> 6;
  int f = frag % NCOF;
  int rest = frag / NCOF;
  int c = rest % NC;
  int t = rest / NC;
  int co = f * 16 + (lane & 15);
  int ci0 = c * 32 + (lane >> 4) * 8;
  f16 buf[8];
  #pragma unroll
  for (int j = 0; j < 8; j++) {
    int ci = ci0 + j;
    buf[j] = (f16)((ci < CIN) ? w[((size_t)co * CIN + ci) * 9 + t] : 0.f);
  }
  *(uint4*)&wt[(size_t)idx * 8] = *(uint4*)buf;
}

// ---------------- dcn weight -> f16 A-frags over K=576 (ci = k*64 + dg*4 + c) ----------------
__global__ __launch_bounds__(256) void wtrans_dcn_mfma_k(const float* __restrict__ w,
                                                         f16* __restrict__ wt) {
  int idx = blockIdx.x * 256 + threadIdx.x;
  if (idx >= 18 * 4 * 64) return;
  int lane = idx & 63;
  int frag = idx >> 6;
  int f = frag & 3;
  int chunk = frag >> 2;
  int co = f * 16 + (lane & 15);
  int ci0 = chunk * 32 + (lane >> 4) * 8;
  f16 buf[8];
  #pragma unroll
  for (int j = 0; j < 8; j++) {
    int ci = ci0 + j;
    int k = ci >> 6, cig = ci & 63;
    buf[j] = (f16)w[((size_t)co * 64 + cig) * 9 + k];
  }
  *(uint4*)&wt[(size_t)idx * 8] = *(uint4*)buf;
}

// x [B][64][H][W] f32 -> xt2 [B][16][H][W][8] f16 : (4ch @ x, 4ch @ min(x+1,127))
__global__ __launch_bounds__(256) void xtrans2_k(const float* __restrict__ x,
                                                 f16* __restrict__ xt2, int B) {
  int idx = blockIdx.x * 256 + threadIdx.x;
  int total = B * 16 * HW;
  if (idx >= total) return;
  int b = idx / (16 * HW);
  int r = idx % (16 * HW);
  int dg = r / HW, p = r % HW;
  int y = p >> 7, xx = p & 127;
  int x1 = min(xx + 1, 127);
  const float* xb = x + ((size_t)b * 64 + dg * 4) * HW + (size_t)y * Ww;
  f16 o[8];
  #pragma unroll
  for (int c = 0; c < 4; c++) {
    o[c] = (f16)xb[(size_t)c * HW + xx];
    o[4 + c] = (f16)xb[(size_t)c * HW + x1];
  }
  *(uint4*)&xt2[(size_t)idx * 8] = *(uint4*)o;
}

// ---------------- conv3x3 via f16 MFMA, 16x8 tile, LDS-staged, T14 prefetch ----------------
template<int CINP, int NC, int NCF, int NCOF, int EPI>
__global__ __launch_bounds__(256) void conv_f16_k(
    const f16* __restrict__ in, const f16* __restrict__ wt,
    const float* __restrict__ bias, f16* __restrict__ out,
    float* __restrict__ offb, f16* __restrict__ mskb,
    const float* __restrict__ flow, int cogroups)
{
  __shared__ u16 lds[180 * 40];
  const int tid = threadIdx.x;
  const int lane = tid & 63, wave = tid >> 6;
  const int b = blockIdx.z / cogroups, cog = blockIdx.z % cogroups;
  const int gx0 = blockIdx.x * 16, gy0 = blockIdx.y * 8;

  f32x4 acc[2][NCF];
  #pragma unroll
  for (int i = 0; i < 2; i++)
    #pragma unroll
    for (int j = 0; j < NCF; j++) acc[i][j] = (f32x4)0.f;

  const f16* inb = in + (size_t)b * PADPX * CINP;

  uint4 rbuf[3];
#define LOADC(cc) { \
    if (tid < 240) { \
      _Pragma("unroll") \
      for (int j = 0; j < 3; j++) { \
        int i = j * 240 + tid; \
        int pidx = i >> 2, q = i & 3; \
        int py = pidx / 18, px = pidx - py * 18; \
        size_t gp = (size_t)((gy0 + py) * PITCH + gx0 + px); \
        rbuf[j] = *(const uint4*)&inb[gp * CINP + (cc) * 32 + q * 8]; \
      } } }
#define WRITEC() { \
    if (tid < 240) { \
      _Pragma("unroll") \
      for (int j = 0; j < 3; j++) { \
        int i = j * 240 + tid; \
        int pidx = i >> 2, q = i & 3; \
        *(uint4*)&lds[pidx * 40 + q * 8] = rbuf[j]; \
      } } }

  LOADC(0);
  for (int c = 0; c < NC; c++) {
    __syncthreads();                 // previous chunk's readers done
    WRITEC();
    if (c + 1 < NC) LOADC(c + 1);    // overlaps MFMA below
    __syncthreads();

    #pragma unroll
    for (int tap = 0; tap < 9; tap++) {
      const int dy = tap / 3, dx = tap % 3;
      f16x8 bfrag[2];
      #pragma unroll
      for (int pl = 0; pl < 2; pl++) {
        int pidx_r = (wave * 2 + pl + dy) * 18 + (lane & 15) + dx;
        bfrag[pl] = *(const f16x8*)&lds[pidx_r * 40 + (lane >> 4) * 8];
      }
      const f16* fA = wt + (((size_t)(tap * NC + c)) * NCOF + cog * NCF) * 512
                      + (size_t)lane * 8;
      #pragma unroll
      for (int cf = 0; cf < NCF; cf++) {
        f16x8 a = *(const f16x8*)&fA[(size_t)cf * 512];
        #pragma unroll
        for (int pl = 0; pl < 2; pl++)
          acc[pl][cf] = __builtin_amdgcn_mfma_f32_16x16x32_f16(a, bfrag[pl], acc[pl][cf], 0, 0, 0);
      }
    }
  }
#undef LOADC
#undef WRITEC

  const int co_l = (lane >> 4) * 4;
  if (EPI == 0) {
    #pragma unroll
    for (int pl = 0; pl < 2; pl++) {
      size_t pp = (size_t)((gy0 + wave * 2 + pl + 1) * PITCH + gx0 + (lane & 15) + 1);
      f16* ob = out + ((size_t)b * PADPX + pp) * (NCOF * 16);
      #pragma unroll
      for (int cf = 0; cf < NCF; cf++) {
        int c0 = (cog * NCF + cf) * 16 + co_l;
        f16 buf[4];
        #pragma unroll
        for (int r = 0; r < 4; r++) {
          float v = acc[pl][cf][r] + bias[c0 + r];
          buf[r] = (f16)((v >= 0.f) ? v : 0.1f * v);
        }
        *(uint2*)&ob[c0] = *(uint2*)buf;
      }
    }
  } else {
    #pragma unroll
    for (int pl = 0; pl < 2; pl++) {
      size_t pix = (size_t)(gy0 + wave * 2 + pl) * Ww + gx0 + (lane & 15);
      float fl0 = flow[((size_t)b * 2 + 0) * HW + pix];
      float fl1 = flow[((size_t)b * 2 + 1) * HW + pix];
      #pragma unroll
      for (int cf = 0; cf < NCF; cf++) {
        int c0 = (cog * NCF + cf) * 16 + co_l;
        #pragma unroll
        for (int r = 0; r < 4; r++) {
          int cc = c0 + r;
          float v = acc[pl][cf][r] + bias[cc];
          if (cc < 288) {
            float e = __expf(2.f * v);
            float t = 1.f - 2.f * __builtin_amdgcn_rcpf(e + 1.f);
            offb[((size_t)b * 288 + cc) * HW + pix] = 10.f * t + ((cc & 1) ? fl0 : fl1);
          } else {
            mskb[((size_t)b * 144 + (cc - 288)) * HW + pix] =
                (f16)__builtin_amdgcn_rcpf(1.f + __expf(-v));
          }
        }
      }
    }
  }
}

// ---------------- fused dcn: 16 px/block, 2048 blocks (8/CU), XCD-swizzled -----------------
// sampler: pxl = tid&15, dg = tid>>4 (one dg/thread, 2 gathers/tap)
// mfma: wave = co-frag (4 waves x 16 co), 2 MFMA/tap, acc = 1 f32x4
__global__ __launch_bounds__(256, 8) void dcn_fused_k(
    const f16* __restrict__ xt2, const float* __restrict__ off,
    const f16* __restrict__ msk, const f16* __restrict__ wtd,
    const float* __restrict__ bias, float* __restrict__ out)
{
  __shared__ u16 buf[2][16][72];
  const int tid = threadIdx.x;
  const int lane = tid & 63, wave = tid >> 6;
  const int bid = blockIdx.x;
  const int nid = (bid & 7) * 256 + (bid >> 3);   // bijective, 2048 = 8*256
  const int b = nid >> 10;
  const int px0 = (nid & 1023) * 16;
  const int pxl = tid & 15;
  const int dg  = tid >> 4;
  const int px = px0 + pxl;
  const int y = px >> 7, x0i = px & 127;

  const float* offp = off + (size_t)b * 288 * HW + px;
  const f16*   mp   = msk + (size_t)b * 144 * HW + px;
  const f16*   xp   = xt2 + (size_t)(b * 16 + dg) * ((size_t)HW * 8);

  f32x4 acc = (f32x4)0.f;

  float dyv[2], dxv[2], mvv[2];
  f16x8 g0, g1;
  float w00, w01, w10, w11;
  int hsel;

#define OFF_LOAD(kk, sl) { \
    dyv[sl] = offp[(size_t)(dg * 18 + 2 * (kk)) * HW]; \
    dxv[sl] = offp[(size_t)(dg * 18 + 2 * (kk) + 1) * HW]; \
    mvv[sl] = (float)mp[(size_t)(dg * 9 + (kk)) * HW]; }

#define GATHER(kk, sl) { \
    float py = (float)(y - 1 + (kk) / 3) + dyv[sl]; \
    float pxx = (float)(x0i - 1 + (kk) % 3) + dxv[sl]; \
    float y0f = floorf(py), x0f = floorf(pxx); \
    float wy = py - y0f, wx = pxx - x0f; \
    int yi = (int)y0f, xi = (int)x0f; \
    bool vy0 = (yi >= 0) & (yi < Hh); \
    bool vy1 = (yi + 1 >= 0) & (yi + 1 < Hh); \
    bool vx0 = (xi >= 0) & (xi < Ww); \
    bool vx1 = (xi + 1 >= 0) & (xi + 1 < Ww); \
    int y0c = min(max(yi, 0), Hh - 1), y1c = min(max(yi + 1, 0), Hh - 1); \
    int xb = min(max(xi, 0), Ww - 1); \
    hsel = min(max(xi + 1, 0), Ww - 1) - xb; \
    float mv = mvv[sl]; \
    w00 = (vy0 && vx0) ? (1.f - wy) * (1.f - wx) * mv : 0.f; \
    w01 = (vy0 && vx1) ? (1.f - wy) * wx * mv : 0.f; \
    w10 = (vy1 && vx0) ? wy * (1.f - wx) * mv : 0.f; \
    w11 = (vy1 && vx1) ? wy * wx * mv : 0.f; \
    g0 = *(const f16x8*)&xp[(size_t)(y0c * Ww + xb) * 8]; \
    g1 = *(const f16x8*)&xp[(size_t)(y1c * Ww + xb) * 8]; }

#define FIN(nb) { \
    f16 o[4]; \
    _Pragma("unroll") \
    for (int c = 0; c < 4; c++) { \
      float a00 = (float)g0[c]; \
      float a01 = hsel ? (float)g0[4 + c] : (float)g0[c]; \
      float a10 = (float)g1[c]; \
      float a11 = hsel ? (float)g1[4 + c] : (float)g1[c]; \
      o[c] = (f16)(a00 * w00 + a01 * w01 + a10 * w10 + a11 * w11); } \
    *(uint2*)&buf[nb][pxl][dg * 4] = *(uint2*)o; }

#define MFMA_TAP(kk) { \
    _Pragma("unroll") \
    for (int ch = 0; ch < 2; ch++) { \
      f16x8 bfr = *(const f16x8*)&buf[(kk) & 1][lane & 15][(lane >> 4) * 8 + ch * 32]; \
      const f16* wc = wtd + ((size_t)((((kk) * 2 + ch) * 4 + wave)) * 64 + (size_t)lane) * 8; \
      f16x8 a = *(const f16x8*)wc; \
      acc = __builtin_amdgcn_mfma_f32_16x16x32_f16(a, bfr, acc, 0, 0, 0); } }

  // prologue: sample tap 0, prefetch offs tap 1
  OFF_LOAD(0, 0);
  GATHER(0, 0);
  OFF_LOAD(1, 1);
  FIN(0);
  __syncthreads();

  #pragma unroll
  for (int k = 0; k < 9; k++) {
    if (k < 8) { GATHER(k + 1, (k + 1) & 1); }  // offs already in flight
    if (k < 7) { OFF_LOAD(k + 2, k & 1); }      // prefetch next-next offs
    MFMA_TAP(k);                                 // covers gather latency
    if (k < 8) { FIN((k + 1) & 1); }            // blend + ds_write next buf
    __syncthreads();
  }

  // epilogue
  const int pxo = px0 + (lane & 15);
  #pragma unroll
  for (int r = 0; r < 4; r++) {
    int co = wave * 16 + (lane >> 4) * 4 + r;
    out[((size_t)b * 64 + co) * HW + pxo] = acc[r] + bias[co];
  }
#undef OFF_LOAD
#undef GATHER
#undef FIN
#undef MFMA_TAP
}

// ---------------- launch ----------------
extern "C" void kernel_launch(void* const* d_in, const int* in_sizes, int n_in,
                              void* d_out, int out_size, void* d_ws, size_t ws_size,
                              hipStream_t stream) {
  const float* x    = (const float*)d_in[0];
  const float* cond = (const float*)d_in[1];
  const float* flow = (const float*)d_in[2];
  const float* w1 = (const float*)d_in[3];
  const float* b1 = (const float*)d_in[4];
  const float* w2 = (const float*)d_in[5];
  const float* b2 = (const float*)d_in[6];
  const float* w3 = (const float*)d_in[7];
  const float* b3 = (const float*)d_in[8];
  const float* w4 = (const float*)d_in[9];
  const float* b4 = (const float*)d_in[10];
  const float* wD = (const float*)d_in[11];
  const float* bD = (const float*)d_in[12];
  float* out = (float*)d_out;
  const int B = 2;

  char* ws = (char*)d_ws;
  f16* condp = (f16*)ws;                         // 2*16900*160*2 = 10,816,000
  f16* hA = (f16*)(ws + 10816000);               // 2*16900*64*2  =  4,326,400
  f16* hB = (f16*)(ws + 15142400);               //                  4,326,400
  char* pw = ws + 19468800;
  float* offb = (float*)pw;          pw += 37748736;
  f16*   mskb = (f16*)pw;            pw += 9437184;
  f16*   xt2  = (f16*)pw;            pw += 8388608;
  f16*   wt1  = (f16*)pw;            pw += 184320;
  f16*   wt2  = (f16*)pw;            pw += 73728;
  f16*   wt3  = (f16*)pw;            pw += 73728;
  f16*   wt4  = (f16*)pw;            pw += 497664;
  f16*   wtd  = (f16*)pw;            pw += 73728;

  // halo zeroing + prep + weight transposes
  zero_edge_k<<<dim3((516 * 20 + 255) / 256, B), 256, 0, stream>>>((u16*)condp, 160);
  zero_edge_k<<<dim3((516 * 8 + 255) / 256, B), 256, 0, stream>>>((u16*)hA, 64);
  zero_edge_k<<<dim3((516 * 8 + 255) / 256, B), 256, 0, stream>>>((u16*)hB, 64);
  prep_cond_k<<<dim3(HW / 256, B), 256, 0, stream>>>(cond, condp);
  xtrans2_k<<<dim3(B * 16 * HW / 256), 256, 0, stream>>>(x, xt2, B);
  wtrans_mfma_k<<<dim3((9 * 5 * 4 * 64 + 255) / 256), 256, 0, stream>>>(w1, wt1, 133, 5, 4);
  wtrans_mfma_k<<<dim3((9 * 2 * 4 * 64 + 255) / 256), 256, 0, stream>>>(w2, wt2, 64, 2, 4);
  wtrans_mfma_k<<<dim3((9 * 2 * 4 * 64 + 255) / 256), 256, 0, stream>>>(w3, wt3, 64, 2, 4);
  wtrans_mfma_k<<<dim3((9 * 2 * 27 * 64 + 255) / 256), 256, 0, stream>>>(w4, wt4, 64, 2, 27);
  wtrans_dcn_mfma_k<<<dim3((18 * 4 * 64 + 255) / 256), 256, 0, stream>>>(wD, wtd);

  // convs (f16 MFMA, 16x8 tiles, staged with T14 prefetch)
  conv_f16_k<160, 5, 1, 4, 0><<<dim3(8, 16, B * 4), 256, 0, stream>>>(
      condp, wt1, b1, hA, nullptr, nullptr, nullptr, 4);
  conv_f16_k<64, 2, 1, 4, 0><<<dim3(8, 16, B * 4), 256, 0, stream>>>(
      hA, wt2, b2, hB, nullptr, nullptr, nullptr, 4);
  conv_f16_k<64, 2, 1, 4, 0><<<dim3(8, 16, B * 4), 256, 0, stream>>>(
      hB, wt3, b3, hA, nullptr, nullptr, nullptr, 4);
  conv_f16_k<64, 2, 3, 27, 2><<<dim3(8, 16, B * 9), 256, 0, stream>>>(
      hA, wt4, b4, nullptr, offb, mskb, flow, 9);

  // fused deformable conv: 16 px/block, 8 blocks/CU, XCD-swizzled
  dcn_fused_k<<<dim3(2048), 256, 0, stream>>>(xt2, offb, mskb, wtd, bD, out);
}

// Round 10
// 154.960 us; speedup vs baseline: 1.2070x; 1.2070x over previous
//
#include <hip/hip_runtime.h>
#include <math.h>

#define Hh 128
#define Ww 128
#define HW (128*128)
#define PITCH 130
#define PADPX (130*130)

typedef unsigned short u16;
typedef unsigned int uint;
typedef _Float16 f16;
typedef __attribute__((ext_vector_type(8))) _Float16 f16x8;
typedef __attribute__((ext_vector_type(4))) _Float16 f16x4;
typedef __attribute__((ext_vector_type(4))) float f32x4;

// ---------------- zero halo edges of padded NHWC f16 buffer ----------------
__global__ __launch_bounds__(256) void zero_edge_k(u16* __restrict__ buf, int cu16) {
  int per_px = cu16 >> 3;           // uint4 chunks per pixel
  int total = 516 * per_px;
  int idx = blockIdx.x * 256 + threadIdx.x;
  int b = blockIdx.y;
  if (idx >= total) return;
  int e = idx / per_px, q = idx - e * per_px;
  int y, x;
  if (e < 130)      { y = 0;   x = e; }
  else if (e < 260) { y = 129; x = e - 130; }
  else { int j = e - 260; y = 1 + (j >> 1); x = (j & 1) ? 129 : 0; }
  *(uint4*)&buf[((size_t)b * PADPX + (size_t)(y * PITCH + x)) * cu16 + q * 8] =
      make_uint4(0, 0, 0, 0);
}

// ---------------- prep: cond [B][133][HW] f32 -> padded NHWC f16 [B][PADPX][160] ----------------
__global__ __launch_bounds__(256) void prep_cond_k(const float* __restrict__ cond,
                                                   f16* __restrict__ out) {
  int p = blockIdx.x * 256 + threadIdx.x;
  int b = blockIdx.y;
  int y = p >> 7, x = p & 127;
  const float* cb = cond + (size_t)b * 133 * HW + p;
  f16* ob = out + ((size_t)b * PADPX + (size_t)((y + 1) * PITCH + x + 1)) * 160;
  for (int c = 0; c < 160; c += 8) {
    f16 buf[8];
    #pragma unroll
    for (int j = 0; j < 8; j++) {
      float v = (c + j < 133) ? cb[(size_t)(c + j) * HW] : 0.f;
      buf[j] = (f16)v;
    }
    *(uint4*)&ob[c] = *(uint4*)buf;
  }
}

// ---------------- conv weight -> f16 MFMA A-frags: frag = (t*NC + c)*NCOF + f ----------------
__global__ __launch_bounds__(256) void wtrans_mfma_k(const float* __restrict__ w,
                                                     f16* __restrict__ wt,
                                                     int CIN, int NC, int NCOF) {
  int idx = blockIdx.x * 256 + threadIdx.x;
  int total = 9 * NC * NCOF * 64;
  if (idx >= total) return;
  int lane = idx & 63;
  int frag = idx >> 6;
  int f = frag % NCOF;
  int rest = frag / NCOF;
  int c = rest % NC;
  int t = rest / NC;
  int co = f * 16 + (lane & 15);
  int ci0 = c * 32 + (lane >> 4) * 8;
  f16 buf[8];
  #pragma unroll
  for (int j = 0; j < 8; j++) {
    int ci = ci0 + j;
    buf[j] = (f16)((ci < CIN) ? w[((size_t)co * CIN + ci) * 9 + t] : 0.f);
  }
  *(uint4*)&wt[(size_t)idx * 8] = *(uint4*)buf;
}

// ---------------- dcn weight -> f16 A-frags over K=576 (ci = k*64 + dg*4 + c) ----------------
__global__ __launch_bounds__(256) void wtrans_dcn_mfma_k(const float* __restrict__ w,
                                                         f16* __restrict__ wt) {
  int idx = blockIdx.x * 256 + threadIdx.x;
  if (idx >= 18 * 4 * 64) return;
  int lane = idx & 63;
  int frag = idx >> 6;
  int f = frag & 3;
  int chunk = frag >> 2;
  int co = f * 16 + (lane & 15);
  int ci0 = chunk * 32 + (lane >> 4) * 8;
  f16 buf[8];
  #pragma unroll
  for (int j = 0; j < 8; j++) {
    int ci = ci0 + j;
    int k = ci >> 6, cig = ci & 63;
    buf[j] = (f16)w[((size_t)co * 64 + cig) * 9 + k];
  }
  *(uint4*)&wt[(size_t)idx * 8] = *(uint4*)buf;
}

// x [B][64][H][W] f32 -> xt2 [B][16][H][W][8] f16 : (4ch @ x, 4ch @ min(x+1,127))
__global__ __launch_bounds__(256) void xtrans2_k(const float* __restrict__ x,
                                                 f16* __restrict__ xt2, int B) {
  int idx = blockIdx.x * 256 + threadIdx.x;
  int total = B * 16 * HW;
  if (idx >= total) return;
  int b = idx / (16 * HW);
  int r = idx % (16 * HW);
  int dg = r / HW, p = r % HW;
  int y = p >> 7, xx = p & 127;
  int x1 = min(xx + 1, 127);
  const float* xb = x + ((size_t)b * 64 + dg * 4) * HW + (size_t)y * Ww;
  f16 o[8];
  #pragma unroll
  for (int c = 0; c < 4; c++) {
    o[c] = (f16)xb[(size_t)c * HW + xx];
    o[4 + c] = (f16)xb[(size_t)c * HW + x1];
  }
  *(uint4*)&xt2[(size_t)idx * 8] = *(uint4*)o;
}

// ---------------- conv3x3 via f16 MFMA, 16x8 tile, LDS-staged (round-8 structure) ----------
template<int CINP, int NC, int NCF, int NCOF, int EPI>
__global__ __launch_bounds__(256) void conv_f16_k(
    const f16* __restrict__ in, const f16* __restrict__ wt,
    const float* __restrict__ bias, f16* __restrict__ out,
    float* __restrict__ offb, f16* __restrict__ mskb,
    const float* __restrict__ flow, int cogroups)
{
  __shared__ u16 lds[180 * 40];
  const int tid = threadIdx.x;
  const int lane = tid & 63, wave = tid >> 6;
  const int b = blockIdx.z / cogroups, cog = blockIdx.z % cogroups;
  const int gx0 = blockIdx.x * 16, gy0 = blockIdx.y * 8;

  f32x4 acc[2][NCF];
  #pragma unroll
  for (int i = 0; i < 2; i++)
    #pragma unroll
    for (int j = 0; j < NCF; j++) acc[i][j] = (f32x4)0.f;

  const f16* inb = in + (size_t)b * PADPX * CINP;

  for (int c = 0; c < NC; c++) {
    __syncthreads();
    // stage 10x18 halo x 32 ci: 180 px * 4 quads of 16B
    for (int i = tid; i < 720; i += 256) {
      int pidx = i >> 2, q = i & 3;
      int py = pidx / 18, px = pidx - py * 18;
      size_t gp = (size_t)((gy0 + py) * PITCH + gx0 + px);
      uint4 v = *(const uint4*)&inb[gp * CINP + c * 32 + q * 8];
      *(uint4*)&lds[pidx * 40 + q * 8] = v;
    }
    __syncthreads();

    #pragma unroll
    for (int tap = 0; tap < 9; tap++) {
      const int dy = tap / 3, dx = tap % 3;
      f16x8 bfrag[2];
      #pragma unroll
      for (int pl = 0; pl < 2; pl++) {
        int pidx_r = (wave * 2 + pl + dy) * 18 + (lane & 15) + dx;
        bfrag[pl] = *(const f16x8*)&lds[pidx_r * 40 + (lane >> 4) * 8];
      }
      const f16* fA = wt + (((size_t)(tap * NC + c)) * NCOF + cog * NCF) * 512
                      + (size_t)lane * 8;
      #pragma unroll
      for (int cf = 0; cf < NCF; cf++) {
        f16x8 a = *(const f16x8*)&fA[(size_t)cf * 512];
        #pragma unroll
        for (int pl = 0; pl < 2; pl++)
          acc[pl][cf] = __builtin_amdgcn_mfma_f32_16x16x32_f16(a, bfrag[pl], acc[pl][cf], 0, 0, 0);
      }
    }
  }

  const int co_l = (lane >> 4) * 4;
  if (EPI == 0) {
    #pragma unroll
    for (int pl = 0; pl < 2; pl++) {
      size_t pp = (size_t)((gy0 + wave * 2 + pl + 1) * PITCH + gx0 + (lane & 15) + 1);
      f16* ob = out + ((size_t)b * PADPX + pp) * (NCOF * 16);
      #pragma unroll
      for (int cf = 0; cf < NCF; cf++) {
        int c0 = (cog * NCF + cf) * 16 + co_l;
        f16 buf[4];
        #pragma unroll
        for (int r = 0; r < 4; r++) {
          float v = acc[pl][cf][r] + bias[c0 + r];
          buf[r] = (f16)((v >= 0.f) ? v : 0.1f * v);
        }
        *(uint2*)&ob[c0] = *(uint2*)buf;
      }
    }
  } else {
    #pragma unroll
    for (int pl = 0; pl < 2; pl++) {
      size_t pix = (size_t)(gy0 + wave * 2 + pl) * Ww + gx0 + (lane & 15);
      float fl0 = flow[((size_t)b * 2 + 0) * HW + pix];
      float fl1 = flow[((size_t)b * 2 + 1) * HW + pix];
      #pragma unroll
      for (int cf = 0; cf < NCF; cf++) {
        int c0 = (cog * NCF + cf) * 16 + co_l;
        #pragma unroll
        for (int r = 0; r < 4; r++) {
          int cc = c0 + r;
          float v = acc[pl][cf][r] + bias[cc];
          if (cc < 288) {
            float e = __expf(2.f * v);
            float t = 1.f - 2.f * __builtin_amdgcn_rcpf(e + 1.f);
            offb[((size_t)b * 288 + cc) * HW + pix] = 10.f * t + ((cc & 1) ? fl0 : fl1);
          } else {
            mskb[((size_t)b * 144 + (cc - 288)) * HW + pix] =
                (f16)__builtin_amdgcn_rcpf(1.f + __expf(-v));
          }
        }
      }
    }
  }
}

// ---------------- fused dcn: 16 px/block, 2048 blocks (8/CU), XCD-swizzled -----------------
// sampler: pxl = tid&15, dg = tid>>4 (one dg/thread, 2 gathers/tap)
// mfma: wave = co-frag (4 waves x 16 co), 2 MFMA/tap, acc = 1 f32x4
__global__ __launch_bounds__(256, 8) void dcn_fused_k(
    const f16* __restrict__ xt2, const float* __restrict__ off,
    const f16* __restrict__ msk, const f16* __restrict__ wtd,
    const float* __restrict__ bias, float* __restrict__ out)
{
  __shared__ u16 buf[2][16][72];
  const int tid = threadIdx.x;
  const int lane = tid & 63, wave = tid >> 6;
  const int bid = blockIdx.x;
  const int nid = (bid & 7) * 256 + (bid >> 3);   // bijective, 2048 = 8*256
  const int b = nid >> 10;
  const int px0 = (nid & 1023) * 16;
  const int pxl = tid & 15;
  const int dg  = tid >> 4;
  const int px = px0 + pxl;
  const int y = px >> 7, x0i = px & 127;

  const float* offp = off + (size_t)b * 288 * HW + px;
  const f16*   mp   = msk + (size_t)b * 144 * HW + px;
  const f16*   xp   = xt2 + (size_t)(b * 16 + dg) * ((size_t)HW * 8);

  f32x4 acc = (f32x4)0.f;

  float dyv[2], dxv[2], mvv[2];
  f16x8 g0, g1;
  float w00, w01, w10, w11;
  int hsel;

#define OFF_LOAD(kk, sl) { \
    dyv[sl] = offp[(size_t)(dg * 18 + 2 * (kk)) * HW]; \
    dxv[sl] = offp[(size_t)(dg * 18 + 2 * (kk) + 1) * HW]; \
    mvv[sl] = (float)mp[(size_t)(dg * 9 + (kk)) * HW]; }

#define GATHER(kk, sl) { \
    float py = (float)(y - 1 + (kk) / 3) + dyv[sl]; \
    float pxx = (float)(x0i - 1 + (kk) % 3) + dxv[sl]; \
    float y0f = floorf(py), x0f = floorf(pxx); \
    float wy = py - y0f, wx = pxx - x0f; \
    int yi = (int)y0f, xi = (int)x0f; \
    bool vy0 = (yi >= 0) & (yi < Hh); \
    bool vy1 = (yi + 1 >= 0) & (yi + 1 < Hh); \
    bool vx0 = (xi >= 0) & (xi < Ww); \
    bool vx1 = (xi + 1 >= 0) & (xi + 1 < Ww); \
    int y0c = min(max(yi, 0), Hh - 1), y1c = min(max(yi + 1, 0), Hh - 1); \
    int xb = min(max(xi, 0), Ww - 1); \
    hsel = min(max(xi + 1, 0), Ww - 1) - xb; \
    float mv = mvv[sl]; \
    w00 = (vy0 && vx0) ? (1.f - wy) * (1.f - wx) * mv : 0.f; \
    w01 = (vy0 && vx1) ? (1.f - wy) * wx * mv : 0.f; \
    w10 = (vy1 && vx0) ? wy * (1.f - wx) * mv : 0.f; \
    w11 = (vy1 && vx1) ? wy * wx * mv : 0.f; \
    g0 = *(const f16x8*)&xp[(size_t)(y0c * Ww + xb) * 8]; \
    g1 = *(const f16x8*)&xp[(size_t)(y1c * Ww + xb) * 8]; }

#define FIN(nb) { \
    f16 o[4]; \
    _Pragma("unroll") \
    for (int c = 0; c < 4; c++) { \
      float a00 = (float)g0[c]; \
      float a01 = hsel ? (float)g0[4 + c] : (float)g0[c]; \
      float a10 = (float)g1[c]; \
      float a11 = hsel ? (float)g1[4 + c] : (float)g1[c]; \
      o[c] = (f16)(a00 * w00 + a01 * w01 + a10 * w10 + a11 * w11); } \
    *(uint2*)&buf[nb][pxl][dg * 4] = *(uint2*)o; }

#define MFMA_TAP(kk) { \
    _Pragma("unroll") \
    for (int ch = 0; ch < 2; ch++) { \
      f16x8 bfr = *(const f16x8*)&buf[(kk) & 1][lane & 15][(lane >> 4) * 8 + ch * 32]; \
      const f16* wc = wtd + ((size_t)((((kk) * 2 + ch) * 4 + wave)) * 64 + (size_t)lane) * 8; \
      f16x8 a = *(const f16x8*)wc; \
      acc = __builtin_amdgcn_mfma_f32_16x16x32_f16(a, bfr, acc, 0, 0, 0); } }

  // prologue: sample tap 0, prefetch offs tap 1
  OFF_LOAD(0, 0);
  GATHER(0, 0);
  OFF_LOAD(1, 1);
  FIN(0);
  __syncthreads();

  #pragma unroll
  for (int k = 0; k < 9; k++) {
    if (k < 8) { GATHER(k + 1, (k + 1) & 1); }  // offs already in flight
    if (k < 7) { OFF_LOAD(k + 2, k & 1); }      // prefetch next-next offs
    MFMA_TAP(k);                                 // covers gather latency
    if (k < 8) { FIN((k + 1) & 1); }            // blend + ds_write next buf
    __syncthreads();
  }

  // epilogue
  const int pxo = px0 + (lane & 15);
  #pragma unroll
  for (int r = 0; r < 4; r++) {
    int co = wave * 16 + (lane >> 4) * 4 + r;
    out[((size_t)b * 64 + co) * HW + pxo] = acc[r] + bias[co];
  }
#undef OFF_LOAD
#undef GATHER
#undef FIN
#undef MFMA_TAP
}

// ---------------- launch ----------------
extern "C" void kernel_launch(void* const* d_in, const int* in_sizes, int n_in,
                              void* d_out, int out_size, void* d_ws, size_t ws_size,
                              hipStream_t stream) {
  const float* x    = (const float*)d_in[0];
  const float* cond = (const float*)d_in[1];
  const float* flow = (const float*)d_in[2];
  const float* w1 = (const float*)d_in[3];
  const float* b1 = (const float*)d_in[4];
  const float* w2 = (const float*)d_in[5];
  const float* b2 = (const float*)d_in[6];
  const float* w3 = (const float*)d_in[7];
  const float* b3 = (const float*)d_in[8];
  const float* w4 = (const float*)d_in[9];
  const float* b4 = (const float*)d_in[10];
  const float* wD = (const float*)d_in[11];
  const float* bD = (const float*)d_in[12];
  float* out = (float*)d_out;
  const int B = 2;

  char* ws = (char*)d_ws;
  f16* condp = (f16*)ws;                         // 2*16900*160*2 = 10,816,000
  f16* hA = (f16*)(ws + 10816000);               // 2*16900*64*2  =  4,326,400
  f16* hB = (f16*)(ws + 15142400);               //                  4,326,400
  char* pw = ws + 19468800;
  float* offb = (float*)pw;          pw += 37748736;
  f16*   mskb = (f16*)pw;            pw += 9437184;
  f16*   xt2  = (f16*)pw;            pw += 8388608;
  f16*   wt1  = (f16*)pw;            pw += 184320;
  f16*   wt2  = (f16*)pw;            pw += 73728;
  f16*   wt3  = (f16*)pw;            pw += 73728;
  f16*   wt4  = (f16*)pw;            pw += 497664;
  f16*   wtd  = (f16*)pw;            pw += 73728;

  // halo zeroing + prep + weight transposes
  zero_edge_k<<<dim3((516 * 20 + 255) / 256, B), 256, 0, stream>>>((u16*)condp, 160);
  zero_edge_k<<<dim3((516 * 8 + 255) / 256, B), 256, 0, stream>>>((u16*)hA, 64);
  zero_edge_k<<<dim3((516 * 8 + 255) / 256, B), 256, 0, stream>>>((u16*)hB, 64);
  prep_cond_k<<<dim3(HW / 256, B), 256, 0, stream>>>(cond, condp);
  xtrans2_k<<<dim3(B * 16 * HW / 256), 256, 0, stream>>>(x, xt2, B);
  wtrans_mfma_k<<<dim3((9 * 5 * 4 * 64 + 255) / 256), 256, 0, stream>>>(w1, wt1, 133, 5, 4);
  wtrans_mfma_k<<<dim3((9 * 2 * 4 * 64 + 255) / 256), 256, 0, stream>>>(w2, wt2, 64, 2, 4);
  wtrans_mfma_k<<<dim3((9 * 2 * 4 * 64 + 255) / 256), 256, 0, stream>>>(w3, wt3, 64, 2, 4);
  wtrans_mfma_k<<<dim3((9 * 2 * 27 * 64 + 255) / 256), 256, 0, stream>>>(w4, wt4, 64, 2, 27);
  wtrans_dcn_mfma_k<<<dim3((18 * 4 * 64 + 255) / 256), 256, 0, stream>>>(wD, wtd);

  // convs (f16 MFMA, 16x8 tiles, round-8 staging)
  conv_f16_k<160, 5, 1, 4, 0><<<dim3(8, 16, B * 4), 256, 0, stream>>>(
      condp, wt1, b1, hA, nullptr, nullptr, nullptr, 4);
  conv_f16_k<64, 2, 1, 4, 0><<<dim3(8, 16, B * 4), 256, 0, stream>>>(
      hA, wt2, b2, hB, nullptr, nullptr, nullptr, 4);
  conv_f16_k<64, 2, 1, 4, 0><<<dim3(8, 16, B * 4), 256, 0, stream>>>(
      hB, wt3, b3, hA, nullptr, nullptr, nullptr, 4);
  conv_f16_k<64, 2, 3, 27, 2><<<dim3(8, 16, B * 9), 256, 0, stream>>>(
      hA, wt4, b4, nullptr, offb, mskb, flow, 9);

  // fused deformable conv: 16 px/block, 8 blocks/CU, XCD-swizzled
  dcn_fused_k<<<dim3(2048), 256, 0, stream>>>(xt2, offb, mskb, wtd, bD, out);
}

// Round 11
// 154.150 us; speedup vs baseline: 1.2133x; 1.0053x over previous
//
#include <hip/hip_runtime.h>
#include <math.h>

#define Hh 128
#define Ww 128
#define HW (128*128)
#define PITCH 130
#define PADPX (130*130)

typedef unsigned short u16;
typedef unsigned int uint;
typedef _Float16 f16;
typedef __attribute__((ext_vector_type(8))) _Float16 f16x8;
typedef __attribute__((ext_vector_type(4))) _Float16 f16x4;
typedef __attribute__((ext_vector_type(4))) float f32x4;

// ---------------- zero halo edges of padded NHWC f16 buffer ----------------
__global__ __launch_bounds__(256) void zero_edge_k(u16* __restrict__ buf, int cu16) {
  int per_px = cu16 >> 3;           // uint4 chunks per pixel
  int total = 516 * per_px;
  int idx = blockIdx.x * 256 + threadIdx.x;
  int b = blockIdx.y;
  if (idx >= total) return;
  int e = idx / per_px, q = idx - e * per_px;
  int y, x;
  if (e < 130)      { y = 0;   x = e; }
  else if (e < 260) { y = 129; x = e - 130; }
  else { int j = e - 260; y = 1 + (j >> 1); x = (j & 1) ? 129 : 0; }
  *(uint4*)&buf[((size_t)b * PADPX + (size_t)(y * PITCH + x)) * cu16 + q * 8] =
      make_uint4(0, 0, 0, 0);
}

// ---------------- prep: cond [B][133][HW] f32 -> padded NHWC f16 [B][PADPX][160] ----------------
__global__ __launch_bounds__(256) void prep_cond_k(const float* __restrict__ cond,
                                                   f16* __restrict__ out) {
  int p = blockIdx.x * 256 + threadIdx.x;
  int b = blockIdx.y;
  int y = p >> 7, x = p & 127;
  const float* cb = cond + (size_t)b * 133 * HW + p;
  f16* ob = out + ((size_t)b * PADPX + (size_t)((y + 1) * PITCH + x + 1)) * 160;
  for (int c = 0; c < 160; c += 8) {
    f16 buf[8];
    #pragma unroll
    for (int j = 0; j < 8; j++) {
      float v = (c + j < 133) ? cb[(size_t)(c + j) * HW] : 0.f;
      buf[j] = (f16)v;
    }
    *(uint4*)&ob[c] = *(uint4*)buf;
  }
}

// ---------------- conv weight -> f16 MFMA A-frags: frag = (t*NC + c)*NCOF + f ----------------
__global__ __launch_bounds__(256) void wtrans_mfma_k(const float* __restrict__ w,
                                                     f16* __restrict__ wt,
                                                     int CIN, int NC, int NCOF) {
  int idx = blockIdx.x * 256 + threadIdx.x;
  int total = 9 * NC * NCOF * 64;
  if (idx >= total) return;
  int lane = idx & 63;
  int frag = idx >> 6;
  int f = frag % NCOF;
  int rest = frag / NCOF;
  int c = rest % NC;
  int t = rest / NC;
  int co = f * 16 + (lane & 15);
  int ci0 = c * 32 + (lane >> 4) * 8;
  f16 buf[8];
  #pragma unroll
  for (int j = 0; j < 8; j++) {
    int ci = ci0 + j;
    buf[j] = (f16)((ci < CIN) ? w[((size_t)co * CIN + ci) * 9 + t] : 0.f);
  }
  *(uint4*)&wt[(size_t)idx * 8] = *(uint4*)buf;
}

// ---------------- dcn weight -> f16 A-frags over K=576 (ci = k*64 + dg*4 + c) ----------------
__global__ __launch_bounds__(256) void wtrans_dcn_mfma_k(const float* __restrict__ w,
                                                         f16* __restrict__ wt) {
  int idx = blockIdx.x * 256 + threadIdx.x;
  if (idx >= 18 * 4 * 64) return;
  int lane = idx & 63;
  int frag = idx >> 6;
  int f = frag & 3;
  int chunk = frag >> 2;
  int co = f * 16 + (lane & 15);
  int ci0 = chunk * 32 + (lane >> 4) * 8;
  f16 buf[8];
  #pragma unroll
  for (int j = 0; j < 8; j++) {
    int ci = ci0 + j;
    int k = ci >> 6, cig = ci & 63;
    buf[j] = (f16)w[((size_t)co * 64 + cig) * 9 + k];
  }
  *(uint4*)&wt[(size_t)idx * 8] = *(uint4*)buf;
}

// x [B][64][H][W] f32 -> xt2 [B][16][H][W][8] f16 : (4ch @ x, 4ch @ min(x+1,127))
__global__ __launch_bounds__(256) void xtrans2_k(const float* __restrict__ x,
                                                 f16* __restrict__ xt2, int B) {
  int idx = blockIdx.x * 256 + threadIdx.x;
  int total = B * 16 * HW;
  if (idx >= total) return;
  int b = idx / (16 * HW);
  int r = idx % (16 * HW);
  int dg = r / HW, p = r % HW;
  int y = p >> 7, xx = p & 127;
  int x1 = min(xx + 1, 127);
  const float* xb = x + ((size_t)b * 64 + dg * 4) * HW + (size_t)y * Ww;
  f16 o[8];
  #pragma unroll
  for (int c = 0; c < 4; c++) {
    o[c] = (f16)xb[(size_t)c * HW + xx];
    o[4 + c] = (f16)xb[(size_t)c * HW + x1];
  }
  *(uint4*)&xt2[(size_t)idx * 8] = *(uint4*)o;
}

// ---------------- conv3x3 via f16 MFMA, 16x8 tile, LDS-staged (round-8 structure) ----------
template<int CINP, int NC, int NCF, int NCOF, int EPI>
__global__ __launch_bounds__(256) void conv_f16_k(
    const f16* __restrict__ in, const f16* __restrict__ wt,
    const float* __restrict__ bias, f16* __restrict__ out,
    float* __restrict__ offb, f16* __restrict__ mskb,
    const float* __restrict__ flow, int cogroups)
{
  __shared__ u16 lds[180 * 40];
  const int tid = threadIdx.x;
  const int lane = tid & 63, wave = tid >> 6;
  const int b = blockIdx.z / cogroups, cog = blockIdx.z % cogroups;
  const int gx0 = blockIdx.x * 16, gy0 = blockIdx.y * 8;

  f32x4 acc[2][NCF];
  #pragma unroll
  for (int i = 0; i < 2; i++)
    #pragma unroll
    for (int j = 0; j < NCF; j++) acc[i][j] = (f32x4)0.f;

  const f16* inb = in + (size_t)b * PADPX * CINP;

  for (int c = 0; c < NC; c++) {
    __syncthreads();
    // stage 10x18 halo x 32 ci: 180 px * 4 quads of 16B
    for (int i = tid; i < 720; i += 256) {
      int pidx = i >> 2, q = i & 3;
      int py = pidx / 18, px = pidx - py * 18;
      size_t gp = (size_t)((gy0 + py) * PITCH + gx0 + px);
      uint4 v = *(const uint4*)&inb[gp * CINP + c * 32 + q * 8];
      *(uint4*)&lds[pidx * 40 + q * 8] = v;
    }
    __syncthreads();

    #pragma unroll
    for (int tap = 0; tap < 9; tap++) {
      const int dy = tap / 3, dx = tap % 3;
      f16x8 bfrag[2];
      #pragma unroll
      for (int pl = 0; pl < 2; pl++) {
        int pidx_r = (wave * 2 + pl + dy) * 18 + (lane & 15) + dx;
        bfrag[pl] = *(const f16x8*)&lds[pidx_r * 40 + (lane >> 4) * 8];
      }
      const f16* fA = wt + (((size_t)(tap * NC + c)) * NCOF + cog * NCF) * 512
                      + (size_t)lane * 8;
      #pragma unroll
      for (int cf = 0; cf < NCF; cf++) {
        f16x8 a = *(const f16x8*)&fA[(size_t)cf * 512];
        #pragma unroll
        for (int pl = 0; pl < 2; pl++)
          acc[pl][cf] = __builtin_amdgcn_mfma_f32_16x16x32_f16(a, bfrag[pl], acc[pl][cf], 0, 0, 0);
      }
    }
  }

  const int co_l = (lane >> 4) * 4;
  if (EPI == 0) {
    #pragma unroll
    for (int pl = 0; pl < 2; pl++) {
      size_t pp = (size_t)((gy0 + wave * 2 + pl + 1) * PITCH + gx0 + (lane & 15) + 1);
      f16* ob = out + ((size_t)b * PADPX + pp) * (NCOF * 16);
      #pragma unroll
      for (int cf = 0; cf < NCF; cf++) {
        int c0 = (cog * NCF + cf) * 16 + co_l;
        f16 buf[4];
        #pragma unroll
        for (int r = 0; r < 4; r++) {
          float v = acc[pl][cf][r] + bias[c0 + r];
          buf[r] = (f16)((v >= 0.f) ? v : 0.1f * v);
        }
        *(uint2*)&ob[c0] = *(uint2*)buf;
      }
    }
  } else {
    #pragma unroll
    for (int pl = 0; pl < 2; pl++) {
      size_t pix = (size_t)(gy0 + wave * 2 + pl) * Ww + gx0 + (lane & 15);
      float fl0 = flow[((size_t)b * 2 + 0) * HW + pix];
      float fl1 = flow[((size_t)b * 2 + 1) * HW + pix];
      #pragma unroll
      for (int cf = 0; cf < NCF; cf++) {
        int c0 = (cog * NCF + cf) * 16 + co_l;
        #pragma unroll
        for (int r = 0; r < 4; r++) {
          int cc = c0 + r;
          float v = acc[pl][cf][r] + bias[cc];
          if (cc < 288) {
            float e = __expf(2.f * v);
            float t = 1.f - 2.f * __builtin_amdgcn_rcpf(e + 1.f);
            offb[((size_t)b * 288 + cc) * HW + pix] = 10.f * t + ((cc & 1) ? fl0 : fl1);
          } else {
            mskb[((size_t)b * 144 + (cc - 288)) * HW + pix] =
                (f16)__builtin_amdgcn_rcpf(1.f + __expf(-v));
          }
        }
      }
    }
  }
}

// ---------------- fused dcn: wave-local, barrier-free, no LDS ----------------
// Each wave owns 16 px x all 64 co. Lane l samples its own B-frag rows:
// task t in 0..3: dg = (t>>1)*8 + (l>>4)*2 + (t&1), px = l&15.
// B-frag half h = [o(task 2h), o(task 2h+1)] built in registers.
__global__ __launch_bounds__(256) void dcn_fused_k(
    const f16* __restrict__ xt2, const float* __restrict__ off,
    const f16* __restrict__ msk, const f16* __restrict__ wtd,
    const float* __restrict__ bias, float* __restrict__ out)
{
  const int tid = threadIdx.x;
  const int lane = tid & 63, wave = tid >> 6;
  const int bid = blockIdx.x;
  const int nid = (bid & 7) * 64 + (bid >> 3);   // bijective XCD swizzle, 512 = 8*64
  const int tile = nid * 4 + wave;               // 0..2047
  const int b = tile >> 10;
  const int px0 = (tile & 1023) * 16;
  const int pxl = lane & 15;
  const int px = px0 + pxl;
  const int y = px >> 7, x0i = px & 127;
  const int qg = lane >> 4;

  const float* offp = off + (size_t)b * 288 * HW + px;
  const f16*   mp   = msk + (size_t)b * 144 * HW + px;
  const f16*   xbase = xt2 + (size_t)b * 16 * ((size_t)HW * 8);

  f32x4 acc0 = (f32x4)0.f, acc1 = (f32x4)0.f, acc2 = (f32x4)0.f, acc3 = (f32x4)0.f;

  #pragma unroll
  for (int k = 0; k < 9; k++) {
    f16 bfa[2][8];
    #pragma unroll
    for (int t = 0; t < 4; t++) {
      const int dg = (t >> 1) * 8 + qg * 2 + (t & 1);
      float dyv = offp[(size_t)(dg * 18 + 2 * k) * HW];
      float dxv = offp[(size_t)(dg * 18 + 2 * k + 1) * HW];
      float mv  = (float)mp[(size_t)(dg * 9 + k) * HW];
      float py  = (float)(y - 1 + k / 3) + dyv;
      float pxx = (float)(x0i - 1 + k % 3) + dxv;
      float y0f = floorf(py), x0f = floorf(pxx);
      float wy = py - y0f, wx = pxx - x0f;
      int yi = (int)y0f, xi = (int)x0f;
      bool vy0 = (yi >= 0) & (yi < Hh);
      bool vy1 = (yi + 1 >= 0) & (yi + 1 < Hh);
      bool vx0 = (xi >= 0) & (xi < Ww);
      bool vx1 = (xi + 1 >= 0) & (xi + 1 < Ww);
      int y0c = min(max(yi, 0), Hh - 1), y1c = min(max(yi + 1, 0), Hh - 1);
      int xb = min(max(xi, 0), Ww - 1);
      int hsel = min(max(xi + 1, 0), Ww - 1) - xb;
      float w00 = (vy0 && vx0) ? (1.f - wy) * (1.f - wx) * mv : 0.f;
      float w01 = (vy0 && vx1) ? (1.f - wy) * wx * mv : 0.f;
      float w10 = (vy1 && vx0) ? wy * (1.f - wx) * mv : 0.f;
      float w11 = (vy1 && vx1) ? wy * wx * mv : 0.f;
      const f16* xp = xbase + (size_t)dg * ((size_t)HW * 8);
      f16x8 g0 = *(const f16x8*)&xp[(size_t)(y0c * Ww + xb) * 8];
      f16x8 g1 = *(const f16x8*)&xp[(size_t)(y1c * Ww + xb) * 8];
      #pragma unroll
      for (int c = 0; c < 4; c++) {
        float a00 = (float)g0[c];
        float a01 = hsel ? (float)g0[4 + c] : (float)g0[c];
        float a10 = (float)g1[c];
        float a11 = hsel ? (float)g1[4 + c] : (float)g1[c];
        bfa[t >> 1][(t & 1) * 4 + c] = (f16)(a00 * w00 + a01 * w01 + a10 * w10 + a11 * w11);
      }
    }
    f16x8 bf0 = *(const f16x8*)&bfa[0][0];
    f16x8 bf1 = *(const f16x8*)&bfa[1][0];
    const f16* wc0 = wtd + ((size_t)((k * 2 + 0) * 4) * 64 + (size_t)lane) * 8;
    const f16* wc1 = wtd + ((size_t)((k * 2 + 1) * 4) * 64 + (size_t)lane) * 8;
    acc0 = __builtin_amdgcn_mfma_f32_16x16x32_f16(*(const f16x8*)&wc0[0],    bf0, acc0, 0, 0, 0);
    acc1 = __builtin_amdgcn_mfma_f32_16x16x32_f16(*(const f16x8*)&wc0[512],  bf0, acc1, 0, 0, 0);
    acc2 = __builtin_amdgcn_mfma_f32_16x16x32_f16(*(const f16x8*)&wc0[1024], bf0, acc2, 0, 0, 0);
    acc3 = __builtin_amdgcn_mfma_f32_16x16x32_f16(*(const f16x8*)&wc0[1536], bf0, acc3, 0, 0, 0);
    acc0 = __builtin_amdgcn_mfma_f32_16x16x32_f16(*(const f16x8*)&wc1[0],    bf1, acc0, 0, 0, 0);
    acc1 = __builtin_amdgcn_mfma_f32_16x16x32_f16(*(const f16x8*)&wc1[512],  bf1, acc1, 0, 0, 0);
    acc2 = __builtin_amdgcn_mfma_f32_16x16x32_f16(*(const f16x8*)&wc1[1024], bf1, acc2, 0, 0, 0);
    acc3 = __builtin_amdgcn_mfma_f32_16x16x32_f16(*(const f16x8*)&wc1[1536], bf1, acc3, 0, 0, 0);
  }

  // epilogue: out[b][co][px], co = f*16 + (lane>>4)*4 + r
  const int pxo = px0 + pxl;
  float* ob = out + (size_t)b * 64 * HW + pxo;
  #pragma unroll
  for (int r = 0; r < 4; r++) {
    int c0 = qg * 4 + r;
    ob[(size_t)(c0) * HW]      = acc0[r] + bias[c0];
    ob[(size_t)(c0 + 16) * HW] = acc1[r] + bias[c0 + 16];
    ob[(size_t)(c0 + 32) * HW] = acc2[r] + bias[c0 + 32];
    ob[(size_t)(c0 + 48) * HW] = acc3[r] + bias[c0 + 48];
  }
}

// ---------------- launch ----------------
extern "C" void kernel_launch(void* const* d_in, const int* in_sizes, int n_in,
                              void* d_out, int out_size, void* d_ws, size_t ws_size,
                              hipStream_t stream) {
  const float* x    = (const float*)d_in[0];
  const float* cond = (const float*)d_in[1];
  const float* flow = (const float*)d_in[2];
  const float* w1 = (const float*)d_in[3];
  const float* b1 = (const float*)d_in[4];
  const float* w2 = (const float*)d_in[5];
  const float* b2 = (const float*)d_in[6];
  const float* w3 = (const float*)d_in[7];
  const float* b3 = (const float*)d_in[8];
  const float* w4 = (const float*)d_in[9];
  const float* b4 = (const float*)d_in[10];
  const float* wD = (const float*)d_in[11];
  const float* bD = (const float*)d_in[12];
  float* out = (float*)d_out;
  const int B = 2;

  char* ws = (char*)d_ws;
  f16* condp = (f16*)ws;                         // 2*16900*160*2 = 10,816,000
  f16* hA = (f16*)(ws + 10816000);               // 2*16900*64*2  =  4,326,400
  f16* hB = (f16*)(ws + 15142400);               //                  4,326,400
  char* pw = ws + 19468800;
  float* offb = (float*)pw;          pw += 37748736;
  f16*   mskb = (f16*)pw;            pw += 9437184;
  f16*   xt2  = (f16*)pw;            pw += 8388608;
  f16*   wt1  = (f16*)pw;            pw += 184320;
  f16*   wt2  = (f16*)pw;            pw += 73728;
  f16*   wt3  = (f16*)pw;            pw += 73728;
  f16*   wt4  = (f16*)pw;            pw += 497664;
  f16*   wtd  = (f16*)pw;            pw += 73728;

  // halo zeroing + prep + weight transposes
  zero_edge_k<<<dim3((516 * 20 + 255) / 256, B), 256, 0, stream>>>((u16*)condp, 160);
  zero_edge_k<<<dim3((516 * 8 + 255) / 256, B), 256, 0, stream>>>((u16*)hA, 64);
  zero_edge_k<<<dim3((516 * 8 + 255) / 256, B), 256, 0, stream>>>((u16*)hB, 64);
  prep_cond_k<<<dim3(HW / 256, B), 256, 0, stream>>>(cond, condp);
  xtrans2_k<<<dim3(B * 16 * HW / 256), 256, 0, stream>>>(x, xt2, B);
  wtrans_mfma_k<<<dim3((9 * 5 * 4 * 64 + 255) / 256), 256, 0, stream>>>(w1, wt1, 133, 5, 4);
  wtrans_mfma_k<<<dim3((9 * 2 * 4 * 64 + 255) / 256), 256, 0, stream>>>(w2, wt2, 64, 2, 4);
  wtrans_mfma_k<<<dim3((9 * 2 * 4 * 64 + 255) / 256), 256, 0, stream>>>(w3, wt3, 64, 2, 4);
  wtrans_mfma_k<<<dim3((9 * 2 * 27 * 64 + 255) / 256), 256, 0, stream>>>(w4, wt4, 64, 2, 27);
  wtrans_dcn_mfma_k<<<dim3((18 * 4 * 64 + 255) / 256), 256, 0, stream>>>(wD, wtd);

  // convs (f16 MFMA, 16x8 tiles, round-8 staging)
  conv_f16_k<160, 5, 1, 4, 0><<<dim3(8, 16, B * 4), 256, 0, stream>>>(
      condp, wt1, b1, hA, nullptr, nullptr, nullptr, 4);
  conv_f16_k<64, 2, 1, 4, 0><<<dim3(8, 16, B * 4), 256, 0, stream>>>(
      hA, wt2, b2, hB, nullptr, nullptr, nullptr, 4);
  conv_f16_k<64, 2, 1, 4, 0><<<dim3(8, 16, B * 4), 256, 0, stream>>>(
      hB, wt3, b3, hA, nullptr, nullptr, nullptr, 4);
  conv_f16_k<64, 2, 3, 27, 2><<<dim3(8, 16, B * 9), 256, 0, stream>>>(
      hA, wt4, b4, nullptr, offb, mskb, flow, 9);

  // fused deformable conv: wave-local, barrier-free
  dcn_fused_k<<<dim3(512), 256, 0, stream>>>(xt2, offb, mskb, wtd, bD, out);
}